// Round 4
// baseline (426.928 us; speedup 1.0000x reference)
//
#include <hip/hip_runtime.h>

#define N_NODES 50000
#define N_EDGES 800000
#define M_IDX   25000
#define G_NODES 32      // nodes per block in the fused layer kernel
#define SCAN_B  256

// ---------------------------------------------------------------------------
// Prep 1: degree histogram
// ---------------------------------------------------------------------------
__global__ __launch_bounds__(256) void hist_kernel(
    const int* __restrict__ dst, int* __restrict__ cnt, int E)
{
    int e = blockIdx.x * blockDim.x + threadIdx.x;
    if (e < E) atomicAdd(&cnt[dst[e]], 1);
}

// ---------------------------------------------------------------------------
// Prep 2: two-level exclusive scan of cnt -> off  (N = 50000, 196 blocks)
// ---------------------------------------------------------------------------
__global__ __launch_bounds__(SCAN_B) void scan1_kernel(
    const int* __restrict__ cnt, int* __restrict__ off,
    int* __restrict__ bsum, int N)
{
    __shared__ int sh[SCAN_B];
    int i = blockIdx.x * SCAN_B + threadIdx.x;
    int v = (i < N) ? cnt[i] : 0;
    sh[threadIdx.x] = v;
    __syncthreads();
    for (int d = 1; d < SCAN_B; d <<= 1) {
        int t = (threadIdx.x >= d) ? sh[threadIdx.x - d] : 0;
        __syncthreads();
        sh[threadIdx.x] += t;
        __syncthreads();
    }
    if (i < N) off[i] = sh[threadIdx.x] - v;          // exclusive
    if (threadIdx.x == SCAN_B - 1) bsum[blockIdx.x] = sh[threadIdx.x];
}

__global__ __launch_bounds__(SCAN_B) void scan2_kernel(int* __restrict__ bsum, int nb)
{
    __shared__ int sh[SCAN_B];
    int v = (threadIdx.x < nb) ? bsum[threadIdx.x] : 0;
    sh[threadIdx.x] = v;
    __syncthreads();
    for (int d = 1; d < SCAN_B; d <<= 1) {
        int t = (threadIdx.x >= d) ? sh[threadIdx.x - d] : 0;
        __syncthreads();
        sh[threadIdx.x] += t;
        __syncthreads();
    }
    if (threadIdx.x < nb) bsum[threadIdx.x] = sh[threadIdx.x] - v;  // exclusive
}

__global__ __launch_bounds__(SCAN_B) void scan3_kernel(
    int* __restrict__ off, const int* __restrict__ bsum,
    int* __restrict__ cursor, int N)
{
    int i = blockIdx.x * SCAN_B + threadIdx.x;
    if (i < N) {
        int o = off[i] + bsum[blockIdx.x];
        off[i] = o;
        cursor[i] = o;
    }
}

// ---------------------------------------------------------------------------
// Prep 3: fill CSR payload: pp[slot] = {pseudo.xyz, pack(src,dst)}
// (node ids < 65536 -> both fit in one 32-bit word)
// ---------------------------------------------------------------------------
__global__ __launch_bounds__(256) void fill_kernel(
    const int*   __restrict__ ei,     // [2,E]
    const float* __restrict__ pos,    // [N,3]
    int*         __restrict__ cursor, // [N] running slot cursor (init = off)
    float4*      __restrict__ pp,     // [E]
    int E)
{
    int e = blockIdx.x * blockDim.x + threadIdx.x;
    if (e >= E) return;
    int s = ei[e];
    int t = ei[E + e];
    float4 pd;
    pd.x = pos[t * 3 + 0] - pos[s * 3 + 0];
    pd.y = pos[t * 3 + 1] - pos[s * 3 + 1];
    pd.z = pos[t * 3 + 2] - pos[s * 3 + 2];
    pd.w = __int_as_float(s | (t << 16));
    int slot = atomicAdd(&cursor[t], 1);
    pp[slot] = pd;
}

// ---------------------------------------------------------------------------
// Fused layer: block owns G_NODES consecutive nodes; 16-lane groups stream
// the block's contiguous CSR slot range, accumulate messages into LDS via
// ds_add_f32; epilogue fuses mean + root GEMV + bias + ReLU.
// ---------------------------------------------------------------------------
template<int CI>
__global__ __launch_bounds__(256) void fused_layer_kernel(
    const float4* __restrict__ pp,    // [E]
    const int*    __restrict__ off,   // [N] CSR offsets
    const int*    __restrict__ cnt,   // [N] degrees
    const float*  __restrict__ h_in,  // [N,CI]
    const float*  __restrict__ lin_w, // [3, CI*16]
    const float*  __restrict__ lin_b, // [CI*16]
    const float*  __restrict__ gamma, // [CI*16]
    const float*  __restrict__ beta,  // [CI*16]
    const float*  __restrict__ root,  // [CI,16]
    const float*  __restrict__ bias,  // [16]
    float*        __restrict__ h_out, // [N,16]
    int N, int E)
{
    __shared__ float sacc[G_NODES * 16];
    const int o = threadIdx.x & 15;
    const int d = CI * 16;
    float W0[CI], W1[CI], W2[CI], B[CI];
#pragma unroll
    for (int i = 0; i < CI; ++i) {
        int j = i * 16 + o;
        float g = gamma[j];
        W0[i] = lin_w[j] * g;
        W1[i] = lin_w[d + j] * g;
        W2[i] = lin_w[2 * d + j] * g;
        B[i]  = fmaf(lin_b[j], g, beta[j]);
    }
    const int n0 = blockIdx.x * G_NODES;
    for (int i = threadIdx.x; i < G_NODES * 16; i += 256) sacc[i] = 0.f;
    __syncthreads();

    const int s0 = off[n0];
    const int s1 = (n0 + G_NODES >= N) ? E : off[n0 + G_NODES];
    const int grp = threadIdx.x >> 4;   // 16 groups of 16 lanes

    // 2-slot unrolled edge loop (slots strided by group; coalesced 64B/wave)
    for (int slot = s0 + grp; slot < s1; slot += 32) {
        const int slotB = slot + 16;
        const bool vB = (slotB < s1);
        float4 pdA = pp[slot];
        float4 pdB = vB ? pp[slotB] : pdA;
        const int pkA = __float_as_int(pdA.w);
        const int pkB = __float_as_int(pdB.w);
        const int sA = pkA & 0xFFFF, tA = ((unsigned)pkA) >> 16;
        const int sB = pkB & 0xFFFF, tB = ((unsigned)pkB) >> 16;
        float xA[CI], xB[CI];
        const float4* xpA = (const float4*)(h_in + (size_t)sA * CI);
        const float4* xpB = (const float4*)(h_in + (size_t)sB * CI);
#pragma unroll
        for (int q = 0; q < CI / 4; ++q) {
            float4 a = xpA[q];
            xA[4 * q + 0] = a.x; xA[4 * q + 1] = a.y;
            xA[4 * q + 2] = a.z; xA[4 * q + 3] = a.w;
            float4 b = xpB[q];
            xB[4 * q + 0] = b.x; xB[4 * q + 1] = b.y;
            xB[4 * q + 2] = b.z; xB[4 * q + 3] = b.w;
        }
        float aA = 0.f, aB = 0.f;
#pragma unroll
        for (int i = 0; i < CI; ++i) {
            float wA = fmaf(pdA.z, W2[i], fmaf(pdA.y, W1[i], fmaf(pdA.x, W0[i], B[i])));
            aA = fmaf(xA[i], fmaxf(wA, 0.f), aA);
            float wB = fmaf(pdB.z, W2[i], fmaf(pdB.y, W1[i], fmaf(pdB.x, W0[i], B[i])));
            aB = fmaf(xB[i], fmaxf(wB, 0.f), aB);
        }
        atomicAdd(&sacc[(tA - n0) * 16 + o], aA);
        if (vB) atomicAdd(&sacc[(tB - n0) * 16 + o], aB);
    }
    __syncthreads();

    // epilogue: mean + root GEMV + bias + ReLU
    for (int i = threadIdx.x; i < G_NODES * 16; i += 256) {
        int n = n0 + (i >> 4);
        if (n >= N) continue;
        int oc = i & 15;
        float deg = (float)cnt[n];
        float r = fmaf(sacc[i], 1.0f / fmaxf(deg, 1.0f), bias[oc]);
        const float4* hp = (const float4*)(h_in + (size_t)n * CI);
#pragma unroll
        for (int q = 0; q < CI / 4; ++q) {
            float4 v = hp[q];
            r = fmaf(v.x, root[(4 * q + 0) * 16 + oc], r);
            r = fmaf(v.y, root[(4 * q + 1) * 16 + oc], r);
            r = fmaf(v.z, root[(4 * q + 2) * 16 + oc], r);
            r = fmaf(v.w, root[(4 * q + 3) * 16 + oc], r);
        }
        h_out[(size_t)n * 16 + oc] = fmaxf(r, 0.f);
    }
}

// ---------------------------------------------------------------------------
// Output gather: out = [h[idx] (M*16) | pos[idx] (M*3) | batch[idx] (M)]
// ---------------------------------------------------------------------------
__global__ __launch_bounds__(256) void gather_kernel(
    const float* __restrict__ h,
    const float* __restrict__ pos,
    const int*   __restrict__ batch,
    const int*   __restrict__ idx,
    float*       __restrict__ out,
    int M)
{
    int j = blockIdx.x * blockDim.x + threadIdx.x;
    if (j >= M) return;
    int n = idx[j];
    float4*       o4 = (float4*)out + (size_t)j * 4;
    const float4* h4 = (const float4*)(h + (size_t)n * 16);
    o4[0] = h4[0]; o4[1] = h4[1]; o4[2] = h4[2]; o4[3] = h4[3];
    float* po = out + (size_t)M * 16 + (size_t)j * 3;
    po[0] = pos[n * 3 + 0];
    po[1] = pos[n * 3 + 1];
    po[2] = pos[n * 3 + 2];
    ((int*)out)[(size_t)M * 19 + j] = batch[n];
}

extern "C" void kernel_launch(void* const* d_in, const int* in_sizes, int n_in,
                              void* d_out, int out_size, void* d_ws, size_t ws_size,
                              hipStream_t stream) {
    const float* x      = (const float*)d_in[0];
    const float* pos    = (const float*)d_in[1];
    const float* lin_w0 = (const float*)d_in[2];
    const float* lin_b0 = (const float*)d_in[3];
    const float* gamma0 = (const float*)d_in[4];
    const float* beta0  = (const float*)d_in[5];
    const float* root0  = (const float*)d_in[6];
    const float* bias0  = (const float*)d_in[7];
    const float* lin_w1 = (const float*)d_in[8];
    const float* lin_b1 = (const float*)d_in[9];
    const float* gamma1 = (const float*)d_in[10];
    const float* beta1  = (const float*)d_in[11];
    const float* root1  = (const float*)d_in[12];
    const float* bias1  = (const float*)d_in[13];
    const float* lin_w2 = (const float*)d_in[14];
    const float* lin_b2 = (const float*)d_in[15];
    const float* gamma2 = (const float*)d_in[16];
    const float* beta2  = (const float*)d_in[17];
    const float* root2  = (const float*)d_in[18];
    const float* bias2  = (const float*)d_in[19];
    const int*   batch  = (const int*)d_in[20];
    const int*   idx    = (const int*)d_in[21];
    const int*   ei     = (const int*)d_in[22];
    const int*   dst    = ei + N_EDGES;
    float*       out    = (float*)d_out;

    // workspace layout (16B aligned)
    float4* pp     = (float4*)d_ws;                         // E float4 (12.8 MB)
    float*  hA     = (float*)(pp + N_EDGES);                // N*16 floats
    float*  hB     = hA + (size_t)N_NODES * 16;             // N*16 floats
    int*    cnt    = (int*)(hB + (size_t)N_NODES * 16);     // N ints
    int*    off    = cnt + N_NODES;                         // N ints
    int*    cursor = off + N_NODES;                         // N ints
    int*    bsum   = cursor + N_NODES;                      // SCAN_B ints

    const int SCAN_BLOCKS  = (N_NODES + SCAN_B - 1) / SCAN_B;  // 196
    const int FUSED_BLOCKS = (N_NODES + G_NODES - 1) / G_NODES; // 1563

    // ---- prep: histogram -> scan -> CSR fill ----
    hipMemsetAsync(cnt, 0, N_NODES * sizeof(int), stream);
    hist_kernel<<<(N_EDGES + 255) / 256, 256, 0, stream>>>(dst, cnt, N_EDGES);
    scan1_kernel<<<SCAN_BLOCKS, SCAN_B, 0, stream>>>(cnt, off, bsum, N_NODES);
    scan2_kernel<<<1, SCAN_B, 0, stream>>>(bsum, SCAN_BLOCKS);
    scan3_kernel<<<SCAN_BLOCKS, SCAN_B, 0, stream>>>(off, bsum, cursor, N_NODES);
    fill_kernel<<<(N_EDGES + 255) / 256, 256, 0, stream>>>(ei, pos, cursor, pp, N_EDGES);

    // ---- 3 fused layers ----
    fused_layer_kernel<8><<<FUSED_BLOCKS, 256, 0, stream>>>(
        pp, off, cnt, x, lin_w0, lin_b0, gamma0, beta0, root0, bias0, hA, N_NODES, N_EDGES);
    fused_layer_kernel<16><<<FUSED_BLOCKS, 256, 0, stream>>>(
        pp, off, cnt, hA, lin_w1, lin_b1, gamma1, beta1, root1, bias1, hB, N_NODES, N_EDGES);
    fused_layer_kernel<16><<<FUSED_BLOCKS, 256, 0, stream>>>(
        pp, off, cnt, hB, lin_w2, lin_b2, gamma2, beta2, root2, bias2, hA, N_NODES, N_EDGES);

    // ---- output gather ----
    gather_kernel<<<(M_IDX + 255) / 256, 256, 0, stream>>>(hA, pos, batch, idx, out, M_IDX);
}

// Round 5
// 349.310 us; speedup vs baseline: 1.2222x; 1.2222x over previous
//
#include <hip/hip_runtime.h>

#define N_NODES 50000
#define N_EDGES 800000
#define M_IDX   25000
#define SCAN_B  256

// ---------------------------------------------------------------------------
// Prep 1: degree histogram
// ---------------------------------------------------------------------------
__global__ __launch_bounds__(256) void hist_kernel(
    const int* __restrict__ dst, int* __restrict__ cnt, int E)
{
    int e = blockIdx.x * blockDim.x + threadIdx.x;
    if (e < E) atomicAdd(&cnt[dst[e]], 1);
}

// ---------------------------------------------------------------------------
// Prep 2: two-level exclusive scan of cnt -> off
// ---------------------------------------------------------------------------
__global__ __launch_bounds__(SCAN_B) void scan1_kernel(
    const int* __restrict__ cnt, int* __restrict__ off,
    int* __restrict__ bsum, int N)
{
    __shared__ int sh[SCAN_B];
    int i = blockIdx.x * SCAN_B + threadIdx.x;
    int v = (i < N) ? cnt[i] : 0;
    sh[threadIdx.x] = v;
    __syncthreads();
    for (int d = 1; d < SCAN_B; d <<= 1) {
        int t = (threadIdx.x >= d) ? sh[threadIdx.x - d] : 0;
        __syncthreads();
        sh[threadIdx.x] += t;
        __syncthreads();
    }
    if (i < N) off[i] = sh[threadIdx.x] - v;          // exclusive
    if (threadIdx.x == SCAN_B - 1) bsum[blockIdx.x] = sh[threadIdx.x];
}

__global__ __launch_bounds__(SCAN_B) void scan2_kernel(int* __restrict__ bsum, int nb)
{
    __shared__ int sh[SCAN_B];
    int v = (threadIdx.x < nb) ? bsum[threadIdx.x] : 0;
    sh[threadIdx.x] = v;
    __syncthreads();
    for (int d = 1; d < SCAN_B; d <<= 1) {
        int t = (threadIdx.x >= d) ? sh[threadIdx.x - d] : 0;
        __syncthreads();
        sh[threadIdx.x] += t;
        __syncthreads();
    }
    if (threadIdx.x < nb) bsum[threadIdx.x] = sh[threadIdx.x] - v;  // exclusive
}

__global__ __launch_bounds__(SCAN_B) void scan3_kernel(
    int* __restrict__ off, const int* __restrict__ bsum,
    int* __restrict__ cursor, int N)
{
    int i = blockIdx.x * SCAN_B + threadIdx.x;
    if (i < N) {
        int o = off[i] + bsum[blockIdx.x];
        off[i] = o;
        cursor[i] = o;
    }
}

// ---------------------------------------------------------------------------
// Prep 3: fill slot-ordered payload: pp[slot] = {pseudo.xyz, pack(src,dst)}
// ---------------------------------------------------------------------------
__global__ __launch_bounds__(256) void fill_kernel(
    const int*   __restrict__ ei,     // [2,E]
    const float* __restrict__ pos,    // [N,3]
    int*         __restrict__ cursor, // [N] running slot cursor (init = off)
    float4*      __restrict__ pp,     // [E]
    int E)
{
    int e = blockIdx.x * blockDim.x + threadIdx.x;
    if (e >= E) return;
    int s = ei[e];
    int t = ei[E + e];
    float4 pd;
    pd.x = pos[t * 3 + 0] - pos[s * 3 + 0];
    pd.y = pos[t * 3 + 1] - pos[s * 3 + 1];
    pd.z = pos[t * 3 + 2] - pos[s * 3 + 2];
    pd.w = __int_as_float(s | (t << 16));
    int slot = atomicAdd(&cursor[t], 1);
    pp[slot] = pd;
}

// ---------------------------------------------------------------------------
// Phase A: per-slot messages, 16 lanes/slot (lane o = out channel), folded
// edge-MLP weights in registers, 4 slots in flight per thread. pp read and
// mbuf write both coalesced; x-row gather random (L2). No atomics.
// ---------------------------------------------------------------------------
template<int CI>
__global__ __launch_bounds__(256) void edge_msg_kernel(
    const float4* __restrict__ pp,     // [E] slot-ordered
    const float*  __restrict__ h_in,   // [N,CI]
    const float*  __restrict__ lin_w,  // [3, CI*16]
    const float*  __restrict__ lin_b,  // [CI*16]
    const float*  __restrict__ gamma,  // [CI*16]
    const float*  __restrict__ beta,   // [CI*16]
    float*        __restrict__ mbuf,   // [E,16] slot-ordered
    int E)
{
    const int o = threadIdx.x & 15;
    const int d = CI * 16;
    float W0[CI], W1[CI], W2[CI], B[CI];
#pragma unroll
    for (int i = 0; i < CI; ++i) {
        int j = i * 16 + o;
        float g = gamma[j];
        W0[i] = lin_w[j] * g;
        W1[i] = lin_w[d + j] * g;
        W2[i] = lin_w[2 * d + j] * g;
        B[i]  = fmaf(lin_b[j], g, beta[j]);
    }
    const int g  = (blockIdx.x * blockDim.x + threadIdx.x) >> 4;
    const int ng = (gridDim.x * blockDim.x) >> 4;

    for (int s0 = g; s0 < E; s0 += 4 * ng) {
        int  sl[4]; bool v[4]; float4 pd[4];
#pragma unroll
        for (int k = 0; k < 4; ++k) {
            sl[k] = s0 + k * ng;
            v[k]  = sl[k] < E;
            pd[k] = pp[v[k] ? sl[k] : 0];
        }
        float x[4][CI];
#pragma unroll
        for (int k = 0; k < 4; ++k) {
            int s = __float_as_int(pd[k].w) & 0xFFFF;
            const float4* xp = (const float4*)(h_in + (size_t)s * CI);
#pragma unroll
            for (int q = 0; q < CI / 4; ++q) {
                float4 a = xp[q];
                x[k][4 * q + 0] = a.x; x[k][4 * q + 1] = a.y;
                x[k][4 * q + 2] = a.z; x[k][4 * q + 3] = a.w;
            }
        }
        float acc[4] = {0.f, 0.f, 0.f, 0.f};
#pragma unroll
        for (int i = 0; i < CI; ++i) {
#pragma unroll
            for (int k = 0; k < 4; ++k) {
                float w = fmaf(pd[k].x, W0[i],
                          fmaf(pd[k].y, W1[i],
                          fmaf(pd[k].z, W2[i], B[i])));
                acc[k] = fmaf(x[k][i], fmaxf(w, 0.f), acc[k]);
            }
        }
#pragma unroll
        for (int k = 0; k < 4; ++k)
            if (v[k]) mbuf[(size_t)sl[k] * 16 + o] = acc[k];
    }
}

// ---------------------------------------------------------------------------
// Phase B: thread per (node, channel). mbuf is slot-ordered == node-ordered,
// so the per-node sum is a contiguous affine-address stream (no indirection).
// Fuses mean + root GEMV + bias + ReLU.
// ---------------------------------------------------------------------------
template<int CI>
__global__ __launch_bounds__(256) void node_out_kernel(
    const int*   __restrict__ off,    // [N]
    const int*   __restrict__ cnt,    // [N]
    const float* __restrict__ mbuf,   // [E,16]
    const float* __restrict__ h_in,   // [N,CI]
    const float* __restrict__ root,   // [CI,16]
    const float* __restrict__ bias,   // [16]
    float*       __restrict__ h_out,  // [N,16]
    int N)
{
    int tid = blockIdx.x * blockDim.x + threadIdx.x;
    if (tid >= N * 16) return;
    const int t = tid >> 4, o = tid & 15;
    const int deg = cnt[t];
    const float* mp = mbuf + (size_t)off[t] * 16 + o;
    float acc = 0.f;
    int p = 0;
    for (; p + 4 <= deg; p += 4) {
        float a0 = mp[(p + 0) * 16];
        float a1 = mp[(p + 1) * 16];
        float a2 = mp[(p + 2) * 16];
        float a3 = mp[(p + 3) * 16];
        acc += (a0 + a1) + (a2 + a3);
    }
    for (; p < deg; ++p) acc += mp[p * 16];

    float r = fmaf(acc, 1.0f / fmaxf((float)deg, 1.0f), bias[o]);
    const float4* hp = (const float4*)(h_in + (size_t)t * CI);
#pragma unroll
    for (int q = 0; q < CI / 4; ++q) {
        float4 v = hp[q];
        r = fmaf(v.x, root[(4 * q + 0) * 16 + o], r);
        r = fmaf(v.y, root[(4 * q + 1) * 16 + o], r);
        r = fmaf(v.z, root[(4 * q + 2) * 16 + o], r);
        r = fmaf(v.w, root[(4 * q + 3) * 16 + o], r);
    }
    h_out[tid] = fmaxf(r, 0.f);
}

// ---------------------------------------------------------------------------
// Output gather: out = [h[idx] (M*16) | pos[idx] (M*3) | batch[idx] (M)]
// ---------------------------------------------------------------------------
__global__ __launch_bounds__(256) void gather_kernel(
    const float* __restrict__ h,
    const float* __restrict__ pos,
    const int*   __restrict__ batch,
    const int*   __restrict__ idx,
    float*       __restrict__ out,
    int M)
{
    int j = blockIdx.x * blockDim.x + threadIdx.x;
    if (j >= M) return;
    int n = idx[j];
    float4*       o4 = (float4*)out + (size_t)j * 4;
    const float4* h4 = (const float4*)(h + (size_t)n * 16);
    o4[0] = h4[0]; o4[1] = h4[1]; o4[2] = h4[2]; o4[3] = h4[3];
    float* po = out + (size_t)M * 16 + (size_t)j * 3;
    po[0] = pos[n * 3 + 0];
    po[1] = pos[n * 3 + 1];
    po[2] = pos[n * 3 + 2];
    ((int*)out)[(size_t)M * 19 + j] = batch[n];
}

extern "C" void kernel_launch(void* const* d_in, const int* in_sizes, int n_in,
                              void* d_out, int out_size, void* d_ws, size_t ws_size,
                              hipStream_t stream) {
    const float* x      = (const float*)d_in[0];
    const float* pos    = (const float*)d_in[1];
    const float* lin_w0 = (const float*)d_in[2];
    const float* lin_b0 = (const float*)d_in[3];
    const float* gamma0 = (const float*)d_in[4];
    const float* beta0  = (const float*)d_in[5];
    const float* root0  = (const float*)d_in[6];
    const float* bias0  = (const float*)d_in[7];
    const float* lin_w1 = (const float*)d_in[8];
    const float* lin_b1 = (const float*)d_in[9];
    const float* gamma1 = (const float*)d_in[10];
    const float* beta1  = (const float*)d_in[11];
    const float* root1  = (const float*)d_in[12];
    const float* bias1  = (const float*)d_in[13];
    const float* lin_w2 = (const float*)d_in[14];
    const float* lin_b2 = (const float*)d_in[15];
    const float* gamma2 = (const float*)d_in[16];
    const float* beta2  = (const float*)d_in[17];
    const float* root2  = (const float*)d_in[18];
    const float* bias2  = (const float*)d_in[19];
    const int*   batch  = (const int*)d_in[20];
    const int*   idx    = (const int*)d_in[21];
    const int*   ei     = (const int*)d_in[22];
    const int*   dst    = ei + N_EDGES;
    float*       out    = (float*)d_out;

    // workspace layout (16B aligned)
    float4* pp     = (float4*)d_ws;                         // E float4 (12.8 MB)
    float*  mbuf   = (float*)(pp + N_EDGES);                // E*16 floats (51.2 MB)
    float*  hA     = mbuf + (size_t)N_EDGES * 16;           // N*16 floats
    float*  hB     = hA + (size_t)N_NODES * 16;             // N*16 floats
    int*    cnt    = (int*)(hB + (size_t)N_NODES * 16);     // N ints
    int*    off    = cnt + N_NODES;                         // N ints
    int*    cursor = off + N_NODES;                         // N ints
    int*    bsum   = cursor + N_NODES;                      // SCAN_B ints

    const int SCAN_BLOCKS = (N_NODES + SCAN_B - 1) / SCAN_B;   // 196
    const int EB = 2048;                                        // phase-A blocks
    const int NB = (N_NODES * 16 + 255) / 256;                  // phase-B blocks

    // ---- prep: histogram -> scan -> slot-ordered fill ----
    hipMemsetAsync(cnt, 0, N_NODES * sizeof(int), stream);
    hist_kernel<<<(N_EDGES + 255) / 256, 256, 0, stream>>>(dst, cnt, N_EDGES);
    scan1_kernel<<<SCAN_BLOCKS, SCAN_B, 0, stream>>>(cnt, off, bsum, N_NODES);
    scan2_kernel<<<1, SCAN_B, 0, stream>>>(bsum, SCAN_BLOCKS);
    scan3_kernel<<<SCAN_BLOCKS, SCAN_B, 0, stream>>>(off, bsum, cursor, N_NODES);
    fill_kernel<<<(N_EDGES + 255) / 256, 256, 0, stream>>>(ei, pos, cursor, pp, N_EDGES);

    // ---- layer 0: ci=8 ----
    edge_msg_kernel<8><<<EB, 256, 0, stream>>>(pp, x, lin_w0, lin_b0, gamma0, beta0, mbuf, N_EDGES);
    node_out_kernel<8><<<NB, 256, 0, stream>>>(off, cnt, mbuf, x, root0, bias0, hA, N_NODES);

    // ---- layer 1: ci=16 ----
    edge_msg_kernel<16><<<EB, 256, 0, stream>>>(pp, hA, lin_w1, lin_b1, gamma1, beta1, mbuf, N_EDGES);
    node_out_kernel<16><<<NB, 256, 0, stream>>>(off, cnt, mbuf, hA, root1, bias1, hB, N_NODES);

    // ---- layer 2: ci=16 ----
    edge_msg_kernel<16><<<EB, 256, 0, stream>>>(pp, hB, lin_w2, lin_b2, gamma2, beta2, mbuf, N_EDGES);
    node_out_kernel<16><<<NB, 256, 0, stream>>>(off, cnt, mbuf, hB, root2, bias2, hA, N_NODES);

    // ---- output gather ----
    gather_kernel<<<(M_IDX + 255) / 256, 256, 0, stream>>>(hA, pos, batch, idx, out, M_IDX);
}